// Round 1
// baseline (371.800 us; speedup 1.0000x reference)
//
#include <hip/hip_runtime.h>

#define SPB 5
#define TPB 256
#define PS  52      // padded (h,w)-plane stride for x  (49 -> 52, 16B-aligned)
#define LS  364     // l-stride = 7*PS
#define XS  2548    // x sample stride = 7*LS
#define H1P 28      // padded h1 plane stride (25 -> 28, 16B-aligned)
#define H1D 140     // 5*H1P
#define H1O 700     // 5*H1D
#define H1S 1400    // 2*H1O  (h1 sample stride)
#define W2OFF 7000  // w2 staging offset inside overlay ( >= SPB*H1S )

__global__ __launch_bounds__(TPB, 3)
void conv4d_fused(const float* __restrict__ x,
                  const float* __restrict__ w1, const float* __restrict__ b1,
                  const float* __restrict__ w2, const float* __restrict__ b2,
                  float* __restrict__ out, int B)
{
    // s_x doubles as: phase1 input x [SPB][7][7][52]
    //                 then (overlay) h1 [SPB][2][5][5][28] + w2 at W2OFF
    __shared__ __align__(16) float s_x[SPB * XS];
    __shared__ __align__(16) float s_w1[164];
    __shared__ float s_b1[2];
    __shared__ float s_b2[4];

    const int t  = threadIdx.x;
    const int s0 = blockIdx.x * SPB;
    const int ns = min(SPB, B - s0);

    // ---- stage w1 + biases
    for (int i = t; i < 162; i += TPB) s_w1[i] = w1[i];
    if (t < 2) s_b1[t] = b1[t];
    if (t < 4) s_b2[t] = b2[t];

    // ---- stage x, inserting 3 pad floats per 49-float (h,w)-plane so every
    //      patch base is 16B-aligned (enables ds_read_b128 in phase 1)
    {
        const float* xp = x + (size_t)s0 * 2401;
        for (int s = 0; s < ns; ++s) {
            const float* xs = xp + s * 2401;
            float* dst = s_x + s * XS;
            for (int i = t; i < 2401; i += TPB) {
                int p = (int)((unsigned)i / 49u);
                dst[p * PS + (i - p * 49)] = xs[i];
            }
        }
    }
    __syncthreads();

    // ---- phase 1: conv1. task=(s,o,l,d) -> 5x5 plane in regs. 250/256 threads.
    //      Accumulators stay in registers across the overlay barrier.
    float acc[5][5];
    int p1_base = 0;
    const bool act1 = t < ns * 50;
    if (act1) {
        int s = t / 50, r = t % 50;
        int o = r / 25; r %= 25;
        int l = r / 5, d = r % 5;
        p1_base = s * H1S + o * H1O + l * H1D + d * H1P;

        const float bias = s_b1[o];
        #pragma unroll
        for (int h = 0; h < 5; ++h)
            #pragma unroll
            for (int w = 0; w < 5; ++w) acc[h][w] = bias;

        const float* xs = s_x + s * XS;
        const float* wo = s_w1 + o * 81;
        #pragma unroll
        for (int kl = 0; kl < 3; ++kl)
        #pragma unroll
        for (int kd = 0; kd < 3; ++kd) {
            float pr[49];
            const float4* q = (const float4*)(xs + (l + kl) * LS + (d + kd) * PS);
            #pragma unroll
            for (int v = 0; v < 12; ++v) {
                float4 f = q[v];
                pr[4 * v + 0] = f.x; pr[4 * v + 1] = f.y;
                pr[4 * v + 2] = f.z; pr[4 * v + 3] = f.w;
            }
            pr[48] = ((const float*)q)[48];
            const float* wp = wo + kl * 27 + kd * 9;
            #pragma unroll
            for (int kh = 0; kh < 3; ++kh)
            #pragma unroll
            for (int kw = 0; kw < 3; ++kw) {
                const float wv = wp[kh * 3 + kw];
                #pragma unroll
                for (int h = 0; h < 5; ++h)
                #pragma unroll
                for (int w = 0; w < 5; ++w)
                    acc[h][w] += pr[(h + kh) * 7 + (w + kw)] * wv;
            }
        }
    }
    __syncthreads();   // all phase-1 reads of s_x complete -> region is dead

    // ---- write h1 (ReLU) into overlay as float4; stage w2 into overlay
    if (act1) {
        float4* hp4 = (float4*)(s_x + p1_base);
        #pragma unroll
        for (int v = 0; v < 6; ++v) {
            float4 f;
            f.x = fmaxf(acc[(4 * v + 0) / 5][(4 * v + 0) % 5], 0.0f);
            f.y = fmaxf(acc[(4 * v + 1) / 5][(4 * v + 1) % 5], 0.0f);
            f.z = fmaxf(acc[(4 * v + 2) / 5][(4 * v + 2) % 5], 0.0f);
            f.w = fmaxf(acc[(4 * v + 3) / 5][(4 * v + 3) % 5], 0.0f);
            hp4[v] = f;
        }
        s_x[p1_base + 24] = fmaxf(acc[4][4], 0.0f);
    }
    for (int i = t; i < 648; i += TPB) s_x[W2OFF + i] = w2[i];
    __syncthreads();

    // ---- phase 2: conv2. task=(s,o2,l,d) -> 3x3 plane in regs. 180/256 threads.
    if (t < ns * 36) {
        int s = t / 36, r = t % 36;
        int o2 = r / 9; r %= 9;
        int l = r / 3, d = r % 3;

        float a2[3][3];
        const float bias = s_b2[o2];
        #pragma unroll
        for (int h = 0; h < 3; ++h)
            #pragma unroll
            for (int w = 0; w < 3; ++w) a2[h][w] = bias;

        #pragma unroll
        for (int c = 0; c < 2; ++c) {
            const float* hs = s_x + s * H1S + c * H1O;
            const float* wb = s_x + W2OFF + o2 * 162 + c * 81;
            #pragma unroll
            for (int kl = 0; kl < 3; ++kl)
            #pragma unroll
            for (int kd = 0; kd < 3; ++kd) {
                float pr[25];
                const float4* q = (const float4*)(hs + (l + kl) * H1D + (d + kd) * H1P);
                #pragma unroll
                for (int v = 0; v < 6; ++v) {
                    float4 f = q[v];
                    pr[4 * v + 0] = f.x; pr[4 * v + 1] = f.y;
                    pr[4 * v + 2] = f.z; pr[4 * v + 3] = f.w;
                }
                pr[24] = ((const float*)q)[24];
                const float* wp = wb + kl * 27 + kd * 9;
                #pragma unroll
                for (int kh = 0; kh < 3; ++kh)
                #pragma unroll
                for (int kw = 0; kw < 3; ++kw) {
                    const float wv = wp[kh * 3 + kw];
                    #pragma unroll
                    for (int h = 0; h < 3; ++h)
                    #pragma unroll
                    for (int w = 0; w < 3; ++w)
                        a2[h][w] += pr[(h + kh) * 5 + (w + kw)] * wv;
                }
            }
        }
        float* op = out + (size_t)(s0 + s) * 324 + o2 * 81 + l * 27 + d * 9;
        #pragma unroll
        for (int h = 0; h < 3; ++h)
        #pragma unroll
        for (int w = 0; w < 3; ++w)
            op[h * 3 + w] = fmaxf(a2[h][w], 0.0f);
    }
}

extern "C" void kernel_launch(void* const* d_in, const int* in_sizes, int n_in,
                              void* d_out, int out_size, void* d_ws, size_t ws_size,
                              hipStream_t stream)
{
    const float* x  = (const float*)d_in[0];
    const float* w1 = (const float*)d_in[1];
    const float* b1 = (const float*)d_in[2];
    const float* w2 = (const float*)d_in[3];
    const float* b2 = (const float*)d_in[4];
    float* out = (float*)d_out;

    const int B = in_sizes[0] / 2401;          // 16384
    const int grid = (B + SPB - 1) / SPB;      // 3277 blocks
    conv4d_fused<<<grid, TPB, 0, stream>>>(x, w1, b1, w2, b2, out, B);
}

// Round 2
// 369.859 us; speedup vs baseline: 1.0052x; 1.0052x over previous
//
#include <hip/hip_runtime.h>

#define SPB 5
#define TPB 256
#define PS  52      // padded x plane stride (49 -> 52, 16B-aligned)
#define LS  364     // 7*PS
#define XS  2548    // 7*LS  (x sample stride)
#define H1P 28      // padded h1 plane stride (25 -> 28, 16B-aligned)
#define H1D 140     // 5*H1P
#define H1O 700     // 5*H1D
#define H1S 1400    // 2*H1O (h1 sample stride)

__global__ __launch_bounds__(TPB, 3)
void conv4d_fused(const float* __restrict__ x,
                  const float* __restrict__ w1, const float* __restrict__ b1,
                  const float* __restrict__ w2, const float* __restrict__ b2,
                  float* __restrict__ out, int B)
{
    // s_x: phase1 input x [SPB][7][7][52]; after phase1, overlaid by
    // h1 [SPB][2][5][5][28] (7000 floats <= 12740). Weights are NOT staged:
    // all weight indices are compile-time constants -> uniform scalar loads.
    __shared__ __align__(16) float s_x[SPB * XS];

    const int t  = threadIdx.x;
    const int s0 = blockIdx.x * SPB;
    const int ns = min(SPB, B - s0);

    // ---- stage x into padded layout [s][l][d][52] (pads never read)
    {
        const float* xp = x + (size_t)s0 * 2401;
        const int n = ns * 2401;
        for (int i = t; i < n; i += TPB) {
            unsigned pa = (unsigned)i / 49u;        // plane idx across samples
            unsigned c  = (unsigned)i - pa * 49u;   // pos within plane
            unsigned s  = pa / 49u;                 // sample
            unsigned p  = pa - s * 49u;             // plane within sample
            s_x[s * XS + p * PS + c] = xp[i];
        }
    }
    __syncthreads();

    // ---- phase 1: task (s,l,d) -> BOTH channels' 5x5 plane in regs.
    //      125 tasks/block. Each 49-float patch feeds 450 FMAs.
    float acc[2][5][5];
    int h1b = 0;
    const bool act1 = t < ns * 25;
    if (act1) {
        const int s = t / 25, r = t % 25;
        const int l = r / 5, d = r % 5;
        h1b = s * H1S + l * H1D + d * H1P;

        #pragma unroll
        for (int o = 0; o < 2; ++o) {
            const float bv = b1[o];                  // uniform -> s_load
            #pragma unroll
            for (int h = 0; h < 5; ++h)
                #pragma unroll
                for (int w = 0; w < 5; ++w) acc[o][h][w] = bv;
        }

        const float* xs = s_x + s * XS;
        #pragma unroll
        for (int kl = 0; kl < 3; ++kl)
        #pragma unroll
        for (int kd = 0; kd < 3; ++kd) {
            float pr[49];
            const float4* q = (const float4*)(xs + (l + kl) * LS + (d + kd) * PS);
            #pragma unroll
            for (int v = 0; v < 12; ++v) {
                const float4 f = q[v];
                pr[4*v+0] = f.x; pr[4*v+1] = f.y;
                pr[4*v+2] = f.z; pr[4*v+3] = f.w;
            }
            pr[48] = ((const float*)q)[48];
            #pragma unroll
            for (int o = 0; o < 2; ++o) {
                const float* wp = w1 + o * 81 + kl * 27 + kd * 9;  // uniform
                #pragma unroll
                for (int kh = 0; kh < 3; ++kh)
                #pragma unroll
                for (int kw = 0; kw < 3; ++kw) {
                    const float wv = wp[kh * 3 + kw];
                    #pragma unroll
                    for (int h = 0; h < 5; ++h)
                    #pragma unroll
                    for (int w = 0; w < 5; ++w)
                        acc[o][h][w] += pr[(h + kh) * 7 + (w + kw)] * wv;
                }
            }
        }
    }
    __syncthreads();   // all phase-1 reads of s_x done -> region dead

    // ---- write h1 (ReLU) into overlay [s][o][l][d][28] as float4
    if (act1) {
        #pragma unroll
        for (int o = 0; o < 2; ++o) {
            float* hp = s_x + h1b + o * H1O;
            #pragma unroll
            for (int v = 0; v < 6; ++v) {
                float4 f;
                f.x = fmaxf(acc[o][(4*v+0)/5][(4*v+0)%5], 0.0f);
                f.y = fmaxf(acc[o][(4*v+1)/5][(4*v+1)%5], 0.0f);
                f.z = fmaxf(acc[o][(4*v+2)/5][(4*v+2)%5], 0.0f);
                f.w = fmaxf(acc[o][(4*v+3)/5][(4*v+3)%5], 0.0f);
                ((float4*)hp)[v] = f;
            }
            hp[24] = fmaxf(acc[o][4][4], 0.0f);
        }
    }
    __syncthreads();

    // ---- phase 2: task (s,l,d) -> ALL 4 channels' 3x3 plane in regs.
    //      45 tasks/block. Each h1 plane read once, feeds 324 FMAs.
    if (t < ns * 9) {
        const int s = t / 9, r = t % 9;
        const int l = r / 3, d = r % 3;

        float a2[4][3][3];
        #pragma unroll
        for (int o2 = 0; o2 < 4; ++o2) {
            const float bv = b2[o2];                 // uniform -> s_load
            #pragma unroll
            for (int h = 0; h < 3; ++h)
                #pragma unroll
                for (int w = 0; w < 3; ++w) a2[o2][h][w] = bv;
        }

        #pragma unroll
        for (int c = 0; c < 2; ++c)
        #pragma unroll
        for (int kl = 0; kl < 3; ++kl)
        #pragma unroll
        for (int kd = 0; kd < 3; ++kd) {
            float pr[25];
            const float4* q = (const float4*)(s_x + s * H1S + c * H1O +
                                              (l + kl) * H1D + (d + kd) * H1P);
            #pragma unroll
            for (int v = 0; v < 6; ++v) {
                const float4 f = q[v];
                pr[4*v+0] = f.x; pr[4*v+1] = f.y;
                pr[4*v+2] = f.z; pr[4*v+3] = f.w;
            }
            pr[24] = ((const float*)q)[24];
            #pragma unroll
            for (int o2 = 0; o2 < 4; ++o2) {
                const float* wp = w2 + o2 * 162 + c * 81 + kl * 27 + kd * 9; // uniform
                #pragma unroll
                for (int kh = 0; kh < 3; ++kh)
                #pragma unroll
                for (int kw = 0; kw < 3; ++kw) {
                    const float wv = wp[kh * 3 + kw];
                    #pragma unroll
                    for (int h = 0; h < 3; ++h)
                    #pragma unroll
                    for (int w = 0; w < 3; ++w)
                        a2[o2][h][w] += pr[(h + kh) * 5 + (w + kw)] * wv;
                }
            }
        }
        #pragma unroll
        for (int o2 = 0; o2 < 4; ++o2) {
            float* op = out + (size_t)(s0 + s) * 324 + o2 * 81 + l * 27 + d * 9;
            #pragma unroll
            for (int h = 0; h < 3; ++h)
            #pragma unroll
            for (int w = 0; w < 3; ++w)
                op[h * 3 + w] = fmaxf(a2[o2][h][w], 0.0f);
        }
    }
}

extern "C" void kernel_launch(void* const* d_in, const int* in_sizes, int n_in,
                              void* d_out, int out_size, void* d_ws, size_t ws_size,
                              hipStream_t stream)
{
    const float* x  = (const float*)d_in[0];
    const float* w1 = (const float*)d_in[1];
    const float* b1 = (const float*)d_in[2];
    const float* w2 = (const float*)d_in[3];
    const float* b2 = (const float*)d_in[4];
    float* out = (float*)d_out;

    const int B = in_sizes[0] / 2401;          // 16384
    const int grid = (B + SPB - 1) / SPB;      // 3277 blocks
    conv4d_fused<<<grid, TPB, 0, stream>>>(x, w1, b1, w2, b2, out, B);
}

// Round 6
// 290.773 us; speedup vs baseline: 1.2787x; 1.2720x over previous
//
#include <hip/hip_runtime.h>

#define SPB 5
#define TPB 256

__global__ __launch_bounds__(TPB, 2)
void conv4d_fused(const float* __restrict__ x,
                  const float* __restrict__ w1, const float* __restrict__ b1,
                  const float* __restrict__ w2, const float* __restrict__ b2,
                  float* __restrict__ out, int B)
{
    // s_x: phase-1 input [s][l*343 + d*49 + h*7 + w] (12005 floats),
    // then overlaid after phase 1 by h1 [s][o*625 + l*125 + d*25 + h*5 + w]
    // (6250 floats). Total LDS ~51.3 KB -> 3 blocks/CU.
    __shared__ float s_x[SPB * 2401];
    __shared__ float s_w1[162];
    __shared__ float s_w2[648];
    __shared__ float s_b1[2];
    __shared__ float s_b2[4];

    const int t  = threadIdx.x;
    const int s0 = blockIdx.x * SPB;
    const int ns = min(SPB, B - s0);

    // ---- stage weights + biases
    for (int i = t; i < 162; i += TPB) s_w1[i] = w1[i];
    for (int i = t; i < 648; i += TPB) s_w2[i] = w2[i];
    if (t < 2) s_b1[t] = b1[t];
    if (t < 4) s_b2[t] = b2[t];

    // ---- stage inputs (flat coalesced copy across the block's samples)
    {
        const float* xp = x + (size_t)s0 * 2401;
        const int n = ns * 2401;
        for (int i = t; i < n; i += TPB) s_x[i] = xp[i];
    }
    __syncthreads();

    // ---- phase 1: task = (s, o, l, d) -> full 5x5 (h,w) plane in regs.
    //      250/256 threads active. Accumulators stay in registers across
    //      the overlay barrier; h1 is written into dead s_x afterwards.
    float acc[5][5];
    int h1b = 0;
    const bool act1 = t < ns * 50;
    if (act1) {
        int s = t / 50;
        int r = t % 50;
        int o = r / 25; r %= 25;
        int l = r / 5, d = r % 5;
        h1b = s * 1250 + o * 625 + l * 125 + d * 25;

        const float bias = s_b1[o];
        #pragma unroll
        for (int h = 0; h < 5; ++h)
            #pragma unroll
            for (int w = 0; w < 5; ++w) acc[h][w] = bias;

        const float* xs = s_x + s * 2401;
        const float* wo = s_w1 + o * 81;
        #pragma unroll
        for (int kl = 0; kl < 3; ++kl)
        #pragma unroll
        for (int kd = 0; kd < 3; ++kd) {
            float p[7][7];
            const float* xp = xs + (l + kl) * 343 + (d + kd) * 49;
            #pragma unroll
            for (int i = 0; i < 49; ++i) p[i / 7][i % 7] = xp[i];
            const float* wp = wo + kl * 27 + kd * 9;
            #pragma unroll
            for (int kh = 0; kh < 3; ++kh)
            #pragma unroll
            for (int kw = 0; kw < 3; ++kw) {
                const float wv = wp[kh * 3 + kw];
                #pragma unroll
                for (int h = 0; h < 5; ++h)
                #pragma unroll
                for (int w = 0; w < 5; ++w)
                    acc[h][w] += p[h + kh][w + kw] * wv;
            }
        }
    }
    __syncthreads();   // all phase-1 reads of s_x complete -> region dead

    // ---- write h1 (ReLU) into the overlay
    if (act1) {
        float* hp = s_x + h1b;
        #pragma unroll
        for (int h = 0; h < 5; ++h)
        #pragma unroll
        for (int w = 0; w < 5; ++w)
            hp[h * 5 + w] = fmaxf(acc[h][w], 0.0f);
    }
    __syncthreads();

    // ---- phase 2: task = (s, o2, l, d) -> full 3x3 (h,w) plane in regs.
    //      180/256 threads active.
    if (t < ns * 36) {
        int s = t / 36;
        int r = t % 36;
        int o2 = r / 9; r %= 9;
        int l = r / 3, d = r % 3;

        float a2[3][3];
        const float bias = s_b2[o2];
        #pragma unroll
        for (int h = 0; h < 3; ++h)
            #pragma unroll
            for (int w = 0; w < 3; ++w) a2[h][w] = bias;

        #pragma unroll
        for (int c = 0; c < 2; ++c) {
            const float* hs = s_x + s * 1250 + c * 625;
            const float* wb = s_w2 + o2 * 162 + c * 81;
            #pragma unroll
            for (int kl = 0; kl < 3; ++kl)
            #pragma unroll
            for (int kd = 0; kd < 3; ++kd) {
                float p[5][5];
                const float* pp = hs + (l + kl) * 125 + (d + kd) * 25;
                #pragma unroll
                for (int i = 0; i < 25; ++i) p[i / 5][i % 5] = pp[i];
                const float* wp = wb + kl * 27 + kd * 9;
                #pragma unroll
                for (int kh = 0; kh < 3; ++kh)
                #pragma unroll
                for (int kw = 0; kw < 3; ++kw) {
                    const float wv = wp[kh * 3 + kw];
                    #pragma unroll
                    for (int h = 0; h < 3; ++h)
                    #pragma unroll
                    for (int w = 0; w < 3; ++w)
                        a2[h][w] += p[h + kh][w + kw] * wv;
                }
            }
        }
        float* op = out + (size_t)(s0 + s) * 324 + o2 * 81 + l * 27 + d * 9;
        #pragma unroll
        for (int h = 0; h < 3; ++h)
        #pragma unroll
        for (int w = 0; w < 3; ++w)
            op[h * 3 + w] = fmaxf(a2[h][w], 0.0f);
    }
}

extern "C" void kernel_launch(void* const* d_in, const int* in_sizes, int n_in,
                              void* d_out, int out_size, void* d_ws, size_t ws_size,
                              hipStream_t stream)
{
    const float* x  = (const float*)d_in[0];
    const float* w1 = (const float*)d_in[1];
    const float* b1 = (const float*)d_in[2];
    const float* w2 = (const float*)d_in[3];
    const float* b2 = (const float*)d_in[4];
    float* out = (float*)d_out;

    const int B = in_sizes[0] / 2401;          // 16384
    const int grid = (B + SPB - 1) / SPB;      // 3277 blocks
    conv4d_fused<<<grid, TPB, 0, stream>>>(x, w1, b1, w2, b2, out, B);
}